// Round 1
// 1141.888 us; speedup vs baseline: 1.1193x; 1.1193x over previous
//
#include <hip/hip_runtime.h>

#define NUSER 100000
#define NITEM 50000
#define NNODE 150000
#define DIM 128
#define NB 3
#define NL 2
#define BN_EPS 1e-5f
#define NT3P 450560             // 440 * 1024, padded NB*NNODE
#define SCAN_BLOCKS 440
#define TILESN 2344             // ceil(NNODE/64)
#define BNBLK 18750             // NNODE*32/256
#define BNABLK 9375             // NNODE*DIM/8/256

typedef unsigned short u16;
typedef _Float16 f16;
typedef __attribute__((ext_vector_type(8))) _Float16 f16x8;
typedef __attribute__((ext_vector_type(8))) unsigned short us8;
typedef __attribute__((ext_vector_type(4))) float f32x4;

__device__ __forceinline__ float h2f(u16 u) { f16 h; __builtin_memcpy(&h, &u, 2); return (float)h; }
__device__ __forceinline__ u16 f2h(float f) { f16 h = (f16)f; u16 u; __builtin_memcpy(&u, &h, 2); return u; }

struct Out3 { u16* p[3]; };
struct WPtrs { const float* s[8]; };

// ---------------- CSR build ----------------

__global__ __launch_bounds__(256) void count_edges(const int* __restrict__ ei,
                                                   const int* __restrict__ et, int E,
                                                   int* __restrict__ cnt) {
    int t = blockIdx.x * 256 + threadIdx.x;
    if (t >= E) return;
    atomicAdd(&cnt[et[t] * NNODE + ei[E + t]], 1);
}

__global__ __launch_bounds__(256) void scan1(const int* __restrict__ cnt, int* __restrict__ bsum) {
    __shared__ int sh[256];
    int tid = threadIdx.x;
    int base = blockIdx.x * 1024 + tid * 4;
    int4 v = *(const int4*)(cnt + base);
    sh[tid] = v.x + v.y + v.z + v.w;
    __syncthreads();
    for (int off = 128; off > 0; off >>= 1) {
        if (tid < off) sh[tid] += sh[tid + off];
        __syncthreads();
    }
    if (tid == 0) bsum[blockIdx.x] = sh[0];
}

__global__ __launch_bounds__(512) void scan2(int* __restrict__ bsum, int nb) {
    __shared__ int sh[512];
    int tid = threadIdx.x;
    sh[tid] = (tid < nb) ? bsum[tid] : 0;
    __syncthreads();
    for (int off = 1; off < 512; off <<= 1) {
        int v = sh[tid];
        int add = (tid >= off) ? sh[tid - off] : 0;
        __syncthreads();
        sh[tid] = v + add;
        __syncthreads();
    }
    if (tid < nb) bsum[tid] = (tid == 0) ? 0 : sh[tid - 1];
}

__global__ __launch_bounds__(256) void scan3(const int* __restrict__ cnt, const int* __restrict__ bsum,
                                             int* __restrict__ row_start, int* __restrict__ cur) {
    __shared__ int sh[256];
    int tid = threadIdx.x;
    int base = blockIdx.x * 1024 + tid * 4;
    int4 v = *(const int4*)(cnt + base);
    sh[tid] = v.x + v.y + v.z + v.w;
    __syncthreads();
    for (int off = 1; off < 256; off <<= 1) {
        int a = sh[tid];
        int add = (tid >= off) ? sh[tid - off] : 0;
        __syncthreads();
        sh[tid] = a + add;
        __syncthreads();
    }
    int excl = ((tid == 0) ? 0 : sh[tid - 1]) + bsum[blockIdx.x];
    int4 o;
    o.x = excl; o.y = excl + v.x; o.z = o.y + v.y; o.w = o.z + v.z;
    *(int4*)(row_start + base) = o;
    *(int4*)(cur + base) = o;
}

__global__ __launch_bounds__(256) void scatter_csr(const int* __restrict__ ei,
                                                   const int* __restrict__ et, int E,
                                                   int* __restrict__ cur, int* __restrict__ adj) {
    int t = blockIdx.x * 256 + threadIdx.x;
    if (t >= E) return;
    int pos = atomicAdd(&cur[et[t] * NNODE + ei[E + t]], 1);
    adj[pos] = ei[t];
}

// ---------------- weight conversion: all 20 mats, transpose + fp16 ----------------
// mat order: 0 user, 1 item, 2..7 Wl, 8..13 Wr, 14 q, 15..17 key, 18 fuse, 19 ref

__global__ __launch_bounds__(256) void wconv_all(WPtrs w, u16* __restrict__ dst) {
    int gid = blockIdx.x * 256 + threadIdx.x;
    if (gid >= 20 * 16384) return;
    int m = gid >> 14, idx = gid & 16383;
    int k = idx & 127, n = idx >> 7;
    const float* src; int li;
    if (m == 0)       { src = w.s[0]; li = 0; }
    else if (m == 1)  { src = w.s[1]; li = 0; }
    else if (m < 8)   { src = w.s[2]; li = m - 2; }
    else if (m < 14)  { src = w.s[3]; li = m - 8; }
    else if (m == 14) { src = w.s[4]; li = 0; }
    else if (m < 18)  { src = w.s[5]; li = m - 15; }
    else if (m == 18) { src = w.s[6]; li = 0; }
    else              { src = w.s[7]; li = 0; }
    dst[(size_t)m * 16384 + idx] = f2h(src[(size_t)li * 16384 + k * 128 + n]);
}

// ---------------- BN+ReLU apply, in place (layer-1 input activation) ----------------

__global__ __launch_bounds__(256) void bn_apply(u16* __restrict__ h,
                                                const float* __restrict__ stats6,
                                                const float* __restrict__ gamma,
                                                const float* __restrict__ beta) {
    __shared__ float sc[DIM];
    __shared__ float sf[DIM];
    const int tid = threadIdx.x;
    const int b = blockIdx.x / BNABLK;
    const int blk = blockIdx.x % BNABLK;
    const int bl = b * NL;   // layer-0 stats
    if (tid < DIM) {
        const float* st = stats6 + bl * 256;
        const float invN = 1.0f / (float)NNODE;
        float mu = st[tid] * invN;
        float var = fmaxf(st[DIM + tid] * invN - mu * mu, 0.f);
        float scv = gamma[bl * DIM + tid] * rsqrtf(var + BN_EPS);
        sc[tid] = scv;
        sf[tid] = beta[bl * DIM + tid] - mu * scv;
    }
    __syncthreads();
    const int i = blk * 256 + tid;          // us8 index within behavior
    const int c8 = (i & 15) * 8;
    u16* p = h + (size_t)b * NNODE * DIM + (size_t)i * 8;
    us8 u = *(const us8*)p;
    us8 o;
#pragma unroll
    for (int j = 0; j < 8; ++j)
        o[j] = f2h(fmaxf(h2f(u[j]) * sc[c8 + j] + sf[c8 + j], 0.f));
    *(us8*)p = o;
}

// ---------------- SAGE layer, all 3 behaviors in one launch ----------------
// grid = 3*TILESN, b = blockIdx/TILESN. Computes pre-BN
//   h_out = mean_gather(h_in)@Wl + bl + h_in@Wr, accumulating BN stats.
// hin must already be the activated features (bn_apply handles layer-1 input).
// Gather layout: 4 lanes per row, 32 cols each -> 4 independent 16B loads per
// edge, edge-pair unrolled (8 loads in flight; ~4x shallower dep chains than
// the 16-lane-per-row layout). Root operand (A2) is read straight from global
// in the MFMA loop; only T1 lives in LDS -> 18.4KB/block, 8 blocks/CU by LDS.

__global__ __launch_bounds__(256, 5) void sage_layer(
    const u16* __restrict__ hin0, const u16* __restrict__ wt_Wl,
    const u16* __restrict__ wt_Wr, const float* __restrict__ sage_bl,
    float* __restrict__ stats6, Out3 outs, int layer,
    const int* __restrict__ adj, const int* __restrict__ row_start,
    const int* __restrict__ cnt) {
    __shared__ u16 T1[64][136];
    __shared__ float sstat[256];
    const int tid = threadIdx.x;
    const int b = blockIdx.x / TILESN;
    const int tile = blockIdx.x % TILESN;
    const int r0 = tile * 64;
    const int bl = b * NL + layer;
    const u16* hin = hin0 + (layer ? (size_t)b * NNODE * DIM : 0);
    const u16* Wl = wt_Wl + (size_t)bl * 16384;
    const u16* Wr = wt_Wr + (size_t)bl * 16384;

    sstat[tid] = 0.f;

    // stage T1: mean-gather, 4 lanes x 32 cols per row
    {
        const int row = tid >> 2;
        const int c0 = (tid & 3) * 32;
        float a[32];
#pragma unroll
        for (int j = 0; j < 32; ++j) a[j] = 0.f;
        const int n = r0 + row;
        if (n < NNODE) {
            const int base = b * NNODE + n;
            const int s0 = row_start[base];
            const int deg = cnt[base];
            int e = 0;
            for (; e + 1 < deg; e += 2) {
                const u16* p1 = hin + (size_t)adj[s0 + e] * DIM + c0;
                const u16* p2 = hin + (size_t)adj[s0 + e + 1] * DIM + c0;
                us8 u0 = *(const us8*)p1;
                us8 u1 = *(const us8*)(p1 + 8);
                us8 u2 = *(const us8*)(p1 + 16);
                us8 u3 = *(const us8*)(p1 + 24);
                us8 v0 = *(const us8*)p2;
                us8 v1 = *(const us8*)(p2 + 8);
                us8 v2 = *(const us8*)(p2 + 16);
                us8 v3 = *(const us8*)(p2 + 24);
#pragma unroll
                for (int j = 0; j < 8; ++j) {
                    a[j]      += h2f(u0[j]) + h2f(v0[j]);
                    a[8 + j]  += h2f(u1[j]) + h2f(v1[j]);
                    a[16 + j] += h2f(u2[j]) + h2f(v2[j]);
                    a[24 + j] += h2f(u3[j]) + h2f(v3[j]);
                }
            }
            if (e < deg) {
                const u16* p1 = hin + (size_t)adj[s0 + e] * DIM + c0;
                us8 u0 = *(const us8*)p1;
                us8 u1 = *(const us8*)(p1 + 8);
                us8 u2 = *(const us8*)(p1 + 16);
                us8 u3 = *(const us8*)(p1 + 24);
#pragma unroll
                for (int j = 0; j < 8; ++j) {
                    a[j]      += h2f(u0[j]);
                    a[8 + j]  += h2f(u1[j]);
                    a[16 + j] += h2f(u2[j]);
                    a[24 + j] += h2f(u3[j]);
                }
            }
            const float s = 1.0f / (float)(deg > 1 ? deg : 1);
#pragma unroll
            for (int j = 0; j < 32; ++j) a[j] *= s;
        }
#pragma unroll
        for (int k = 0; k < 4; ++k) {
            us8 o;
#pragma unroll
            for (int j = 0; j < 8; ++j) o[j] = f2h(a[8 * k + j]);
            *(us8*)&T1[row][c0 + 8 * k] = o;
        }
    }
    __syncthreads();

    // dual MFMA GEMM: A1 from LDS, A2 direct from global (L1-hot)
    const int wave = tid >> 6, lane = tid & 63, q = lane >> 4, rlo = lane & 15;
    const f16x8 zf = (f16x8)(f16)0.f;
    f32x4 acc[4][2];
#pragma unroll
    for (int t = 0; t < 4; ++t) { acc[t][0] = (f32x4)0.f; acc[t][1] = (f32x4)0.f; }
#pragma unroll
    for (int kc = 0; kc < DIM; kc += 32) {
        f16x8 b1v[2], b2v[2];
#pragma unroll
        for (int c = 0; c < 2; ++c) {
            b1v[c] = *(const f16x8*)(Wl + (size_t)(wave * 32 + 16 * c + rlo) * DIM + kc + q * 8);
            b2v[c] = *(const f16x8*)(Wr + (size_t)(wave * 32 + 16 * c + rlo) * DIM + kc + q * 8);
        }
#pragma unroll
        for (int t = 0; t < 4; ++t) {
            f16x8 a1 = *(const f16x8*)&T1[16 * t + rlo][kc + q * 8];
            int rr = r0 + 16 * t + rlo;
            f16x8 a2 = (rr < NNODE) ? *(const f16x8*)(hin + (size_t)rr * DIM + kc + q * 8) : zf;
            acc[t][0] = __builtin_amdgcn_mfma_f32_16x16x32_f16(a1, b1v[0], acc[t][0], 0, 0, 0);
            acc[t][1] = __builtin_amdgcn_mfma_f32_16x16x32_f16(a1, b1v[1], acc[t][1], 0, 0, 0);
            acc[t][0] = __builtin_amdgcn_mfma_f32_16x16x32_f16(a2, b2v[0], acc[t][0], 0, 0, 0);
            acc[t][1] = __builtin_amdgcn_mfma_f32_16x16x32_f16(a2, b2v[1], acc[t][1], 0, 0, 0);
        }
    }

    const int col0 = wave * 32 + rlo, col1 = col0 + 16;
    const float bb0 = sage_bl[bl * DIM + col0], bb1 = sage_bl[bl * DIM + col1];
    u16* C = outs.p[b];
    float rs0 = 0, rq0 = 0, rs1 = 0, rq1 = 0;
#pragma unroll
    for (int t = 0; t < 4; ++t) {
#pragma unroll
        for (int r = 0; r < 4; ++r) {
            int row = r0 + 16 * t + q * 4 + r;
            if (row >= NNODE) continue;
            float v0 = acc[t][0][r] + bb0;
            float v1 = acc[t][1][r] + bb1;
            rs0 += v0; rq0 += v0 * v0; rs1 += v1; rq1 += v1 * v1;
            C[(size_t)row * DIM + col0] = f2h(v0);
            C[(size_t)row * DIM + col1] = f2h(v1);
        }
    }
    // reduce the 4 lanes (q=0..3) that share col0/col1 before LDS atomics
    rs0 += __shfl_xor(rs0, 16); rs0 += __shfl_xor(rs0, 32);
    rq0 += __shfl_xor(rq0, 16); rq0 += __shfl_xor(rq0, 32);
    rs1 += __shfl_xor(rs1, 16); rs1 += __shfl_xor(rs1, 32);
    rq1 += __shfl_xor(rq1, 16); rq1 += __shfl_xor(rq1, 32);
    if (q == 0) {
        atomicAdd(&sstat[col0], rs0);
        atomicAdd(&sstat[DIM + col0], rq0);
        atomicAdd(&sstat[col1], rs1);
        atomicAdd(&sstat[DIM + col1], rq1);
    }
    __syncthreads();
    if (tid < DIM) {
        float* so = stats6 + bl * 256;
        atomicAdd(&so[tid], sstat[tid]);
        atomicAdd(&so[DIM + tid], sstat[DIM + tid]);
    }
}

// ---------------- final BN + residual, all 3 behaviors ----------------

__global__ __launch_bounds__(256) void bn_final(Out3 ins, const float* __restrict__ stats6,
                                                const float* __restrict__ gamma,
                                                const float* __restrict__ beta,
                                                const u16* __restrict__ xh,
                                                u16* __restrict__ stackb) {
    int blk = blockIdx.x;
    int b = blk / BNBLK;
    int t = (blk % BNBLK) * 256 + threadIdx.x;
    int n = t >> 5;
    int d = (t & 31) * 4;
    const int bl = b * NL + 1;
    const float invN = 1.0f / (float)NNODE;
    const float* st = stats6 + bl * 256;
    float4 s = *(const float4*)&st[d];
    float4 sq = *(const float4*)&st[DIM + d];
    float4 g = *(const float4*)&gamma[bl * DIM + d];
    float4 be = *(const float4*)&beta[bl * DIM + d];
    float mx = s.x * invN, my = s.y * invN, mz = s.z * invN, mw = s.w * invN;
    float cx = g.x * rsqrtf(fmaxf(sq.x * invN - mx * mx, 0.f) + BN_EPS);
    float cy = g.y * rsqrtf(fmaxf(sq.y * invN - my * my, 0.f) + BN_EPS);
    float cz = g.z * rsqrtf(fmaxf(sq.z * invN - mz * mz, 0.f) + BN_EPS);
    float cw = g.w * rsqrtf(fmaxf(sq.w * invN - mw * mw, 0.f) + BN_EPS);
    size_t off = (size_t)n * DIM + d;
    ushort4 hv = *(const ushort4*)(ins.p[b] + off);
    ushort4 xv = *(const ushort4*)(xh + off);
    ushort4 o;
    o.x = f2h((h2f(hv.x) - mx) * cx + be.x + h2f(xv.x));
    o.y = f2h((h2f(hv.y) - my) * cy + be.y + h2f(xv.y));
    o.z = f2h((h2f(hv.z) - mz) * cz + be.z + h2f(xv.z));
    o.w = f2h((h2f(hv.w) - mw) * cw + be.w + h2f(xv.w));
    *(ushort4*)(stackb + (size_t)b * NNODE * DIM + off) = o;
}

// ---------------- plain MFMA GEMM (fp16 weights), 64x128 tile ----------------
// flags: 1=relu, 8=A f32, 32=C f16 (else f32), 64=logits epilogue, 128=batched by behavior

__global__ __launch_bounds__(256) void gemm_p(
    const void* __restrict__ Av, const u16* __restrict__ Wt,
    const float* __restrict__ bias, void* __restrict__ Cv, int M, int tiles,
    const float* __restrict__ Qf, float* __restrict__ logits, int flags) {
    int bi = 0, tile = blockIdx.x;
    if (flags & 128) { bi = blockIdx.x / tiles; tile = blockIdx.x % tiles; }
    const u16* A16 = (const u16*)Av + ((flags & 128) ? (size_t)bi * NNODE * DIM : 0);
    const float* A32 = (const float*)Av;
    const u16* W = Wt + (size_t)bi * 16384;
    const float* bs = bias + bi * DIM;
    const int r0 = tile * 64;
    const int tid = threadIdx.x;
    const int wave = tid >> 6, lane = tid & 63, q = lane >> 4, rlo = lane & 15;
    f32x4 acc[4][2];
#pragma unroll
    for (int t = 0; t < 4; ++t) { acc[t][0] = (f32x4)0.f; acc[t][1] = (f32x4)0.f; }
    const f16x8 zf = (f16x8)(f16)0.f;
#pragma unroll
    for (int kc = 0; kc < DIM; kc += 32) {
        f16x8 av[4], bv[2];
#pragma unroll
        for (int t = 0; t < 4; ++t) {
            int row = r0 + 16 * t + rlo;
            if (row < M) {
                if (flags & 8) {
                    const float* p = A32 + (size_t)row * DIM + kc + q * 8;
                    float4 x0 = *(const float4*)p;
                    float4 x1 = *(const float4*)(p + 4);
                    f16x8 tmp;
                    tmp[0] = (f16)x0.x; tmp[1] = (f16)x0.y; tmp[2] = (f16)x0.z; tmp[3] = (f16)x0.w;
                    tmp[4] = (f16)x1.x; tmp[5] = (f16)x1.y; tmp[6] = (f16)x1.z; tmp[7] = (f16)x1.w;
                    av[t] = tmp;
                } else {
                    av[t] = *(const f16x8*)(A16 + (size_t)row * DIM + kc + q * 8);
                }
            } else {
                av[t] = zf;
            }
        }
#pragma unroll
        for (int c = 0; c < 2; ++c)
            bv[c] = *(const f16x8*)(W + (size_t)(wave * 32 + 16 * c + rlo) * DIM + kc + q * 8);
#pragma unroll
        for (int t = 0; t < 4; ++t) {
            acc[t][0] = __builtin_amdgcn_mfma_f32_16x16x32_f16(av[t], bv[0], acc[t][0], 0, 0, 0);
            acc[t][1] = __builtin_amdgcn_mfma_f32_16x16x32_f16(av[t], bv[1], acc[t][1], 0, 0, 0);
        }
    }

    const int col0 = wave * 32 + rlo, col1 = col0 + 16;
    const float bb0 = bs[col0], bb1 = bs[col1];

    if (flags & 64) {
#pragma unroll
        for (int t = 0; t < 4; ++t) {
#pragma unroll
            for (int r = 0; r < 4; ++r) {
                int row = r0 + 16 * t + q * 4 + r;
                if (row < M) {
                    float v = (acc[t][0][r] + bb0) * Qf[(size_t)row * DIM + col0]
                            + (acc[t][1][r] + bb1) * Qf[(size_t)row * DIM + col1];
                    v += __shfl_xor(v, 1);
                    v += __shfl_xor(v, 2);
                    v += __shfl_xor(v, 4);
                    v += __shfl_xor(v, 8);
                    if (rlo == 0) atomicAdd(&logits[row * NB + bi], v);
                }
            }
        }
        return;
    }

#pragma unroll
    for (int t = 0; t < 4; ++t) {
#pragma unroll
        for (int r = 0; r < 4; ++r) {
            int row = r0 + 16 * t + q * 4 + r;
            if (row >= M) continue;
            float v0 = acc[t][0][r] + bb0;
            float v1 = acc[t][1][r] + bb1;
            if (flags & 1) { v0 = fmaxf(v0, 0.f); v1 = fmaxf(v1, 0.f); }
            if (flags & 32) {
                ((u16*)Cv)[(size_t)row * DIM + col0] = f2h(v0);
                ((u16*)Cv)[(size_t)row * DIM + col1] = f2h(v1);
            } else {
                ((float*)Cv)[(size_t)row * DIM + col0] = v0;
                ((float*)Cv)[(size_t)row * DIM + col1] = v1;
            }
        }
    }
}

// ---------------- softmax-weighted stack sum + fuse GEMM ----------------

__global__ __launch_bounds__(256) void fuse_gemm(
    const u16* __restrict__ stk, const float* __restrict__ logits,
    const u16* __restrict__ Wt, const float* __restrict__ bias,
    u16* __restrict__ C) {
    __shared__ u16 T[64][136];
    const int tid = threadIdx.x;
    const int r0 = blockIdx.x * 64;
    for (int i = tid; i < 1024; i += 256) {
        int r = i >> 4, c8 = (i & 15) * 8;
        int n = r0 + r;
        us8 o;
        if (n < NNODE) {
            float l0 = logits[n * NB + 0];
            float l1 = logits[n * NB + 1];
            float l2 = logits[n * NB + 2];
            float mm = fmaxf(l0, fmaxf(l1, l2));
            float e0 = expf(l0 - mm), e1 = expf(l1 - mm), e2 = expf(l2 - mm);
            float inv = 1.0f / (e0 + e1 + e2);
            float w0 = e0 * inv, w1 = e1 * inv, w2 = e2 * inv;
            size_t off = (size_t)n * DIM + c8;
            us8 u0 = *(const us8*)(stk + off);
            us8 u1 = *(const us8*)(stk + (size_t)NNODE * DIM + off);
            us8 u2 = *(const us8*)(stk + (size_t)2 * NNODE * DIM + off);
#pragma unroll
            for (int j = 0; j < 8; ++j)
                o[j] = f2h(w0 * h2f(u0[j]) + w1 * h2f(u1[j]) + w2 * h2f(u2[j]));
        } else {
            o = (us8)(u16)0;
        }
        *(us8*)&T[r][c8] = o;
    }
    __syncthreads();

    const int wave = tid >> 6, lane = tid & 63, q = lane >> 4, rlo = lane & 15;
    f32x4 acc[4][2];
#pragma unroll
    for (int t = 0; t < 4; ++t) { acc[t][0] = (f32x4)0.f; acc[t][1] = (f32x4)0.f; }
#pragma unroll
    for (int kc = 0; kc < DIM; kc += 32) {
        f16x8 av[4], bv[2];
#pragma unroll
        for (int t = 0; t < 4; ++t)
            av[t] = *(const f16x8*)&T[16 * t + rlo][kc + q * 8];
#pragma unroll
        for (int c = 0; c < 2; ++c)
            bv[c] = *(const f16x8*)(Wt + (size_t)(wave * 32 + 16 * c + rlo) * DIM + kc + q * 8);
#pragma unroll
        for (int t = 0; t < 4; ++t) {
            acc[t][0] = __builtin_amdgcn_mfma_f32_16x16x32_f16(av[t], bv[0], acc[t][0], 0, 0, 0);
            acc[t][1] = __builtin_amdgcn_mfma_f32_16x16x32_f16(av[t], bv[1], acc[t][1], 0, 0, 0);
        }
    }
    const int col0 = wave * 32 + rlo, col1 = col0 + 16;
    const float bb0 = bias[col0], bb1 = bias[col1];
#pragma unroll
    for (int t = 0; t < 4; ++t) {
#pragma unroll
        for (int r = 0; r < 4; ++r) {
            int row = r0 + 16 * t + q * 4 + r;
            if (row >= NNODE) continue;
            C[(size_t)row * DIM + col0] = f2h(acc[t][0][r] + bb0);
            C[(size_t)row * DIM + col1] = f2h(acc[t][1][r] + bb1);
        }
    }
}

// ---------------- launch ----------------

extern "C" void kernel_launch(void* const* d_in, const int* in_sizes, int n_in,
                              void* d_out, int out_size, void* d_ws, size_t ws_size,
                              hipStream_t stream) {
    const int* edge_index    = (const int*)d_in[0];
    const int* edge_type     = (const int*)d_in[1];
    const float* item_feats  = (const float*)d_in[2];
    const float* user_emb    = (const float*)d_in[3];
    const float* user_proj_b = (const float*)d_in[5];
    const float* item_proj_b = (const float*)d_in[7];
    const float* sage_bl  = (const float*)d_in[9];
    const float* bn_gamma = (const float*)d_in[11];
    const float* bn_beta  = (const float*)d_in[12];
    const float* query_b  = (const float*)d_in[14];
    const float* key_b    = (const float*)d_in[16];
    const float* fuse_b   = (const float*)d_in[18];
    const float* refine_b = (const float*)d_in[20];
    const int E = in_sizes[1];

    const size_t ND = (size_t)NNODE * DIM;
    char* w = (char*)d_ws;
    u16* xh = (u16*)w;          w += ND * 2;              // initial x, fp16
    u16* stackb = (u16*)w;      w += NB * ND * 2;         // pre-BN l0 h -> activated -> final outs
    u16* fbuf = (u16*)w;        w += ND * 2;              // hpre slice 0 / fused
    int* cnt = (int*)w;         w += (size_t)NT3P * 4;
    int* row_start = (int*)w;   w += (size_t)NT3P * 4;
    int* cur = (int*)w;         w += (size_t)NT3P * 4;
    int* adj = (int*)w;         w += (size_t)E * 4;
    float* logits = (float*)w;  w += (size_t)NNODE * NB * 4;
    u16* wt = (u16*)w;          w += (size_t)20 * 16384 * 2;
    int* bsum = (int*)w;        w += 2048;
    float* stats6 = (float*)w;  w += 6 * 256 * 4;

    const u16* wt_user = wt;
    const u16* wt_item = wt + 16384;
    const u16* wt_Wl   = wt + 2 * 16384;
    const u16* wt_Wr   = wt + 8 * 16384;
    const u16* wt_q    = wt + 14 * 16384;
    const u16* wt_key  = wt + 15 * 16384;
    const u16* wt_fuse = wt + 18 * 16384;
    const u16* wt_ref  = wt + 19 * 16384;

    u16* dout16 = (u16*)d_out;   // during SAGE: hpre slices 1,2; later Qf f32 / final out
    float* Qf = (float*)d_out;

    // ---- CSR build + weight conversion ----
    hipMemsetAsync(cnt, 0, (size_t)NT3P * 4, stream);
    hipMemsetAsync(logits, 0, (size_t)NNODE * NB * 4, stream);
    hipMemsetAsync(stats6, 0, 6 * 256 * 4, stream);
    int gE = (E + 255) / 256;
    count_edges<<<gE, 256, 0, stream>>>(edge_index, edge_type, E, cnt);
    scan1<<<SCAN_BLOCKS, 256, 0, stream>>>(cnt, bsum);
    scan2<<<1, 512, 0, stream>>>(bsum, SCAN_BLOCKS);
    scan3<<<SCAN_BLOCKS, 256, 0, stream>>>(cnt, bsum, row_start, cur);
    scatter_csr<<<gE, 256, 0, stream>>>(edge_index, edge_type, E, cur, adj);

    WPtrs wp;
    wp.s[0] = (const float*)d_in[4];
    wp.s[1] = (const float*)d_in[6];
    wp.s[2] = (const float*)d_in[8];
    wp.s[3] = (const float*)d_in[10];
    wp.s[4] = (const float*)d_in[13];
    wp.s[5] = (const float*)d_in[15];
    wp.s[6] = (const float*)d_in[17];
    wp.s[7] = (const float*)d_in[19];
    wconv_all<<<1280, 256, 0, stream>>>(wp, wt);

    // ---- initial projection (f32 in, fp16 out) ----
    const int TU = (NUSER + 63) / 64, TI = (NITEM + 63) / 64;
    gemm_p<<<TU, 256, 0, stream>>>(user_emb, wt_user, user_proj_b, xh,
                                   NUSER, TU, nullptr, nullptr, 8 | 32);
    gemm_p<<<TI, 256, 0, stream>>>(item_feats, wt_item, item_proj_b, xh + (size_t)NUSER * DIM,
                                   NITEM, TI, nullptr, nullptr, 8 | 32);

    // ---- SAGE: layer0 -> activate layer0 output in place -> layer1 ----
    Out3 out_l0, out_l1;
    for (int b = 0; b < NB; ++b) out_l0.p[b] = stackb + (size_t)b * ND;
    out_l1.p[0] = fbuf;
    out_l1.p[1] = dout16;
    out_l1.p[2] = dout16 + ND;

    sage_layer<<<NB * TILESN, 256, 0, stream>>>(xh, wt_Wl, wt_Wr, sage_bl,
                                                stats6, out_l0, 0,
                                                adj, row_start, cnt);
    bn_apply<<<NB * BNABLK, 256, 0, stream>>>(stackb, stats6, bn_gamma, bn_beta);
    sage_layer<<<NB * TILESN, 256, 0, stream>>>(stackb, wt_Wl, wt_Wr, sage_bl,
                                                stats6, out_l1, 1,
                                                adj, row_start, cnt);
    bn_final<<<NB * BNBLK, 256, 0, stream>>>(out_l1, stats6, bn_gamma, bn_beta,
                                             xh, stackb);

    // ---- attention fusion ----
    gemm_p<<<TILESN, 256, 0, stream>>>(xh, wt_q, query_b, Qf,
                                       NNODE, TILESN, nullptr, nullptr, 0);       // Q -> d_out f32
    gemm_p<<<NB * TILESN, 256, 0, stream>>>(stackb, wt_key, key_b, nullptr,
                                            NNODE, TILESN, Qf, logits, 64 | 128); // logits
    fuse_gemm<<<TILESN, 256, 0, stream>>>(stackb, logits, wt_fuse, fuse_b, fbuf); // fused -> fbuf
    gemm_p<<<TILESN, 256, 0, stream>>>(fbuf, wt_ref, refine_b, d_out,
                                       NNODE, TILESN, nullptr, nullptr, 1);       // relu -> d_out
}

// Round 2
// 1009.486 us; speedup vs baseline: 1.2662x; 1.1312x over previous
//
#include <hip/hip_runtime.h>

#define NUSER 100000
#define NITEM 50000
#define NNODE 150000
#define DIM 128
#define NB 3
#define NL 2
#define BN_EPS 1e-5f
#define NT3P 450560             // 440 * 1024, padded NB*NNODE
#define SCAN_BLOCKS 440
#define TILESN 2344             // ceil(NNODE/64)
#define BNABLK 9375             // NNODE*DIM/8/256

typedef unsigned short u16;
typedef _Float16 f16;
typedef __attribute__((ext_vector_type(8))) _Float16 f16x8;
typedef __attribute__((ext_vector_type(8))) unsigned short us8;
typedef __attribute__((ext_vector_type(4))) float f32x4;

__device__ __forceinline__ float h2f(u16 u) { f16 h; __builtin_memcpy(&h, &u, 2); return (float)h; }
__device__ __forceinline__ u16 f2h(float f) { f16 h = (f16)f; u16 u; __builtin_memcpy(&u, &h, 2); return u; }

struct Out3 { u16* p[3]; };
struct WPtrs { const float* s[8]; };

// ---------------- CSR build ----------------

__global__ __launch_bounds__(256) void count_edges(const int* __restrict__ ei,
                                                   const int* __restrict__ et, int E,
                                                   int* __restrict__ cnt) {
    int t = blockIdx.x * 256 + threadIdx.x;
    if (t >= E) return;
    atomicAdd(&cnt[et[t] * NNODE + ei[E + t]], 1);
}

__global__ __launch_bounds__(256) void scan1(const int* __restrict__ cnt, int* __restrict__ bsum) {
    __shared__ int sh[256];
    int tid = threadIdx.x;
    int base = blockIdx.x * 1024 + tid * 4;
    int4 v = *(const int4*)(cnt + base);
    sh[tid] = v.x + v.y + v.z + v.w;
    __syncthreads();
    for (int off = 128; off > 0; off >>= 1) {
        if (tid < off) sh[tid] += sh[tid + off];
        __syncthreads();
    }
    if (tid == 0) bsum[blockIdx.x] = sh[0];
}

__global__ __launch_bounds__(512) void scan2(int* __restrict__ bsum, int nb) {
    __shared__ int sh[512];
    int tid = threadIdx.x;
    sh[tid] = (tid < nb) ? bsum[tid] : 0;
    __syncthreads();
    for (int off = 1; off < 512; off <<= 1) {
        int v = sh[tid];
        int add = (tid >= off) ? sh[tid - off] : 0;
        __syncthreads();
        sh[tid] = v + add;
        __syncthreads();
    }
    if (tid < nb) bsum[tid] = (tid == 0) ? 0 : sh[tid - 1];
}

__global__ __launch_bounds__(256) void scan3(const int* __restrict__ cnt, const int* __restrict__ bsum,
                                             int* __restrict__ row_start, int* __restrict__ cur) {
    __shared__ int sh[256];
    int tid = threadIdx.x;
    int base = blockIdx.x * 1024 + tid * 4;
    int4 v = *(const int4*)(cnt + base);
    sh[tid] = v.x + v.y + v.z + v.w;
    __syncthreads();
    for (int off = 1; off < 256; off <<= 1) {
        int a = sh[tid];
        int add = (tid >= off) ? sh[tid - off] : 0;
        __syncthreads();
        sh[tid] = a + add;
        __syncthreads();
    }
    int excl = ((tid == 0) ? 0 : sh[tid - 1]) + bsum[blockIdx.x];
    int4 o;
    o.x = excl; o.y = excl + v.x; o.z = o.y + v.y; o.w = o.z + v.z;
    *(int4*)(row_start + base) = o;
    *(int4*)(cur + base) = o;
}

__global__ __launch_bounds__(256) void scatter_csr(const int* __restrict__ ei,
                                                   const int* __restrict__ et, int E,
                                                   int* __restrict__ cur, int* __restrict__ adj) {
    int t = blockIdx.x * 256 + threadIdx.x;
    if (t >= E) return;
    int pos = atomicAdd(&cur[et[t] * NNODE + ei[E + t]], 1);
    adj[pos] = ei[t];
}

// ---------------- weight conversion: all 20 mats, transpose + fp16 ----------------
// mat order: 0 user, 1 item, 2..7 Wl, 8..13 Wr, 14 q, 15..17 key, 18 fuse, 19 ref

__global__ __launch_bounds__(256) void wconv_all(WPtrs w, u16* __restrict__ dst) {
    int gid = blockIdx.x * 256 + threadIdx.x;
    if (gid >= 20 * 16384) return;
    int m = gid >> 14, idx = gid & 16383;
    int k = idx & 127, n = idx >> 7;
    const float* src; int li;
    if (m == 0)       { src = w.s[0]; li = 0; }
    else if (m == 1)  { src = w.s[1]; li = 0; }
    else if (m < 8)   { src = w.s[2]; li = m - 2; }
    else if (m < 14)  { src = w.s[3]; li = m - 8; }
    else if (m == 14) { src = w.s[4]; li = 0; }
    else if (m < 18)  { src = w.s[5]; li = m - 15; }
    else if (m == 18) { src = w.s[6]; li = 0; }
    else              { src = w.s[7]; li = 0; }
    dst[(size_t)m * 16384 + idx] = f2h(src[(size_t)li * 16384 + k * 128 + n]);
}

// ---------------- BN+ReLU apply, in place (layer-1 input activation) ----------------

__global__ __launch_bounds__(256) void bn_apply(u16* __restrict__ h,
                                                const float* __restrict__ stats6,
                                                const float* __restrict__ gamma,
                                                const float* __restrict__ beta) {
    __shared__ float sc[DIM];
    __shared__ float sf[DIM];
    const int tid = threadIdx.x;
    const int b = blockIdx.x / BNABLK;
    const int blk = blockIdx.x % BNABLK;
    const int bl = b * NL;   // layer-0 stats
    if (tid < DIM) {
        const float* st = stats6 + bl * 256;
        const float invN = 1.0f / (float)NNODE;
        float mu = st[tid] * invN;
        float var = fmaxf(st[DIM + tid] * invN - mu * mu, 0.f);
        float scv = gamma[bl * DIM + tid] * rsqrtf(var + BN_EPS);
        sc[tid] = scv;
        sf[tid] = beta[bl * DIM + tid] - mu * scv;
    }
    __syncthreads();
    const int i = blk * 256 + tid;          // us8 index within behavior
    const int c8 = (i & 15) * 8;
    u16* p = h + (size_t)b * NNODE * DIM + (size_t)i * 8;
    us8 u = *(const us8*)p;
    us8 o;
#pragma unroll
    for (int j = 0; j < 8; ++j)
        o[j] = f2h(fmaxf(h2f(u[j]) * sc[c8 + j] + sf[c8 + j], 0.f));
    *(us8*)p = o;
}

// ---------------- SAGE layer, all 3 behaviors in one launch ----------------
// grid = 3*TILESN, b = blockIdx/TILESN. Computes pre-BN
//   h_out = mean_gather(h_in)@Wl + bl + h_in@Wr, accumulating BN stats.
// Gather: 4 lanes/row x 32 cols, QUAD edge unroll (4 adj + 16 feature loads in
// flight -> ~2 dependent-latency trips for the wave-max degree ~8).
// Layer-1 outputs for b=1,2 are written in TILE-BLOCK layout into d_out
// (tile t occupies bytes [t*32768, t*32768+32768): slice1 rows then slice2
// rows), so the attn_fuse block for tile t owns exactly that byte range and
// can overwrite it with the final f32 output. Last (partial) tile goes to a
// small ws tail buffer to stay inside d_out.

__global__ __launch_bounds__(256, 4) void sage_layer(
    const u16* __restrict__ hin0, const u16* __restrict__ wt_Wl,
    const u16* __restrict__ wt_Wr, const float* __restrict__ sage_bl,
    float* __restrict__ stats6, Out3 outs, int layer,
    const int* __restrict__ adj, const int* __restrict__ row_start,
    const int* __restrict__ cnt) {
    __shared__ u16 T1[64][136];
    __shared__ float sstat[256];
    const int tid = threadIdx.x;
    const int b = blockIdx.x / TILESN;
    const int tile = blockIdx.x % TILESN;
    const int r0 = tile * 64;
    const int bl = b * NL + layer;
    const u16* hin = hin0 + (layer ? (size_t)b * NNODE * DIM : 0);
    const u16* Wl = wt_Wl + (size_t)bl * 16384;
    const u16* Wr = wt_Wr + (size_t)bl * 16384;

    sstat[tid] = 0.f;

    // stage T1: mean-gather, 4 lanes x 32 cols per row, quad edge unroll
    {
        const int row = tid >> 2;
        const int c0 = (tid & 3) * 32;
        float a[32];
#pragma unroll
        for (int j = 0; j < 32; ++j) a[j] = 0.f;
        const int n = r0 + row;
        if (n < NNODE) {
            const int base = b * NNODE + n;
            const int s0 = row_start[base];
            const int deg = cnt[base];
            int e = 0;
            for (; e + 3 < deg; e += 4) {
                const int i0 = adj[s0 + e],     i1 = adj[s0 + e + 1];
                const int i2 = adj[s0 + e + 2], i3 = adj[s0 + e + 3];
                const u16* p0 = hin + (size_t)i0 * DIM + c0;
                const u16* p1 = hin + (size_t)i1 * DIM + c0;
                const u16* p2 = hin + (size_t)i2 * DIM + c0;
                const u16* p3 = hin + (size_t)i3 * DIM + c0;
                us8 u00 = *(const us8*)p0,        u01 = *(const us8*)(p0 + 8);
                us8 u02 = *(const us8*)(p0 + 16), u03 = *(const us8*)(p0 + 24);
                us8 u10 = *(const us8*)p1,        u11 = *(const us8*)(p1 + 8);
                us8 u12 = *(const us8*)(p1 + 16), u13 = *(const us8*)(p1 + 24);
                us8 u20 = *(const us8*)p2,        u21 = *(const us8*)(p2 + 8);
                us8 u22 = *(const us8*)(p2 + 16), u23 = *(const us8*)(p2 + 24);
                us8 u30 = *(const us8*)p3,        u31 = *(const us8*)(p3 + 8);
                us8 u32 = *(const us8*)(p3 + 16), u33 = *(const us8*)(p3 + 24);
#pragma unroll
                for (int j = 0; j < 8; ++j) {
                    a[j]      += (h2f(u00[j]) + h2f(u10[j])) + (h2f(u20[j]) + h2f(u30[j]));
                    a[8 + j]  += (h2f(u01[j]) + h2f(u11[j])) + (h2f(u21[j]) + h2f(u31[j]));
                    a[16 + j] += (h2f(u02[j]) + h2f(u12[j])) + (h2f(u22[j]) + h2f(u32[j]));
                    a[24 + j] += (h2f(u03[j]) + h2f(u13[j])) + (h2f(u23[j]) + h2f(u33[j]));
                }
            }
            if (e + 1 < deg) {
                const u16* p1 = hin + (size_t)adj[s0 + e] * DIM + c0;
                const u16* p2 = hin + (size_t)adj[s0 + e + 1] * DIM + c0;
                us8 u0 = *(const us8*)p1,        u1 = *(const us8*)(p1 + 8);
                us8 u2 = *(const us8*)(p1 + 16), u3 = *(const us8*)(p1 + 24);
                us8 v0 = *(const us8*)p2,        v1 = *(const us8*)(p2 + 8);
                us8 v2 = *(const us8*)(p2 + 16), v3 = *(const us8*)(p2 + 24);
#pragma unroll
                for (int j = 0; j < 8; ++j) {
                    a[j]      += h2f(u0[j]) + h2f(v0[j]);
                    a[8 + j]  += h2f(u1[j]) + h2f(v1[j]);
                    a[16 + j] += h2f(u2[j]) + h2f(v2[j]);
                    a[24 + j] += h2f(u3[j]) + h2f(v3[j]);
                }
                e += 2;
            }
            if (e < deg) {
                const u16* p1 = hin + (size_t)adj[s0 + e] * DIM + c0;
                us8 u0 = *(const us8*)p1,        u1 = *(const us8*)(p1 + 8);
                us8 u2 = *(const us8*)(p1 + 16), u3 = *(const us8*)(p1 + 24);
#pragma unroll
                for (int j = 0; j < 8; ++j) {
                    a[j]      += h2f(u0[j]);
                    a[8 + j]  += h2f(u1[j]);
                    a[16 + j] += h2f(u2[j]);
                    a[24 + j] += h2f(u3[j]);
                }
            }
            const float s = 1.0f / (float)(deg > 1 ? deg : 1);
#pragma unroll
            for (int j = 0; j < 32; ++j) a[j] *= s;
        }
#pragma unroll
        for (int k = 0; k < 4; ++k) {
            us8 o;
#pragma unroll
            for (int j = 0; j < 8; ++j) o[j] = f2h(a[8 * k + j]);
            *(us8*)&T1[row][c0 + 8 * k] = o;
        }
    }
    __syncthreads();

    // dual MFMA GEMM: A1 from LDS, A2 direct from global (L1-hot)
    const int wave = tid >> 6, lane = tid & 63, q = lane >> 4, rlo = lane & 15;
    const f16x8 zf = (f16x8)(f16)0.f;
    f32x4 acc[4][2];
#pragma unroll
    for (int t = 0; t < 4; ++t) { acc[t][0] = (f32x4)0.f; acc[t][1] = (f32x4)0.f; }
#pragma unroll
    for (int kc = 0; kc < DIM; kc += 32) {
        f16x8 b1v[2], b2v[2];
#pragma unroll
        for (int c = 0; c < 2; ++c) {
            b1v[c] = *(const f16x8*)(Wl + (size_t)(wave * 32 + 16 * c + rlo) * DIM + kc + q * 8);
            b2v[c] = *(const f16x8*)(Wr + (size_t)(wave * 32 + 16 * c + rlo) * DIM + kc + q * 8);
        }
#pragma unroll
        for (int t = 0; t < 4; ++t) {
            f16x8 a1 = *(const f16x8*)&T1[16 * t + rlo][kc + q * 8];
            int rr = r0 + 16 * t + rlo;
            f16x8 a2 = (rr < NNODE) ? *(const f16x8*)(hin + (size_t)rr * DIM + kc + q * 8) : zf;
            acc[t][0] = __builtin_amdgcn_mfma_f32_16x16x32_f16(a1, b1v[0], acc[t][0], 0, 0, 0);
            acc[t][1] = __builtin_amdgcn_mfma_f32_16x16x32_f16(a1, b1v[1], acc[t][1], 0, 0, 0);
            acc[t][0] = __builtin_amdgcn_mfma_f32_16x16x32_f16(a2, b2v[0], acc[t][0], 0, 0, 0);
            acc[t][1] = __builtin_amdgcn_mfma_f32_16x16x32_f16(a2, b2v[1], acc[t][1], 0, 0, 0);
        }
    }

    const int col0 = wave * 32 + rlo, col1 = col0 + 16;
    const float bb0 = sage_bl[bl * DIM + col0], bb1 = sage_bl[bl * DIM + col1];
    const bool tiled = (layer == 1) && (b > 0);
    u16* Cb;
    if (!tiled) {
        Cb = outs.p[b];
    } else {
        Cb = ((tile == TILESN - 1) ? outs.p[2]
                                   : outs.p[1] + (size_t)tile * 16384)
             + (size_t)(b - 1) * 8192;
    }
    float rs0 = 0, rq0 = 0, rs1 = 0, rq1 = 0;
#pragma unroll
    for (int t = 0; t < 4; ++t) {
#pragma unroll
        for (int r = 0; r < 4; ++r) {
            int rloc = 16 * t + q * 4 + r;
            int row = r0 + rloc;
            if (row >= NNODE) continue;
            float v0 = acc[t][0][r] + bb0;
            float v1 = acc[t][1][r] + bb1;
            rs0 += v0; rq0 += v0 * v0; rs1 += v1; rq1 += v1 * v1;
            size_t off = tiled ? (size_t)rloc * DIM : (size_t)row * DIM;
            Cb[off + col0] = f2h(v0);
            Cb[off + col1] = f2h(v1);
        }
    }
    rs0 += __shfl_xor(rs0, 16); rs0 += __shfl_xor(rs0, 32);
    rq0 += __shfl_xor(rq0, 16); rq0 += __shfl_xor(rq0, 32);
    rs1 += __shfl_xor(rs1, 16); rs1 += __shfl_xor(rs1, 32);
    rq1 += __shfl_xor(rq1, 16); rq1 += __shfl_xor(rq1, 32);
    if (q == 0) {
        atomicAdd(&sstat[col0], rs0);
        atomicAdd(&sstat[DIM + col0], rq0);
        atomicAdd(&sstat[col1], rs1);
        atomicAdd(&sstat[DIM + col1], rq1);
    }
    __syncthreads();
    if (tid < DIM) {
        float* so = stats6 + bl * 256;
        atomicAdd(&so[tid], sstat[tid]);
        atomicAdd(&so[DIM + tid], sstat[DIM + tid]);
    }
}

// ---------------- fused epilogue: BN+residual, Q/K logits, softmax, fuse, refine ----------------
// One block per 64-row tile. Reads h_pre (b0 linear from fbuf; b1,2 tiled from
// d_out / tail) + xh; writes the final f32 output over its own d_out tile block.
// fuse uses the identity (diag(w)S)@Wf = diag(w)(S@Wf): weights applied in the
// epilogue, no fused-tile materialization.

__global__ __launch_bounds__(256) void attn_fuse(
    const u16* __restrict__ hpre0, const u16* __restrict__ hpre12,
    const u16* __restrict__ tailb, const float* __restrict__ stats6,
    const float* __restrict__ gamma, const float* __restrict__ beta,
    const u16* __restrict__ xh, const u16* __restrict__ wt,
    const float* __restrict__ query_b, const float* __restrict__ key_b,
    const float* __restrict__ fuse_b, const float* __restrict__ refine_b,
    float* __restrict__ out) {
    __shared__ __attribute__((aligned(16))) u16 St[3][64][136];
    __shared__ float sc[3][DIM], sf[3][DIM];
    __shared__ float slog[64][4];
    __shared__ float swt[64][4];
    const int tid = threadIdx.x;
    const int tile = blockIdx.x;
    const int r0 = tile * 64;
    const u16* wt_q    = wt + 14 * 16384;
    const u16* wt_key  = wt + 15 * 16384;
    const u16* wt_fuse = wt + 18 * 16384;
    const u16* wt_ref  = wt + 19 * 16384;

    if (tid < DIM) {
        const float invN = 1.0f / (float)NNODE;
#pragma unroll
        for (int b = 0; b < NB; ++b) {
            const int bl = b * NL + 1;
            const float* st = stats6 + bl * 256;
            float mu = st[tid] * invN;
            float var = fmaxf(st[DIM + tid] * invN - mu * mu, 0.f);
            float c = gamma[bl * DIM + tid] * rsqrtf(var + BN_EPS);
            sc[b][tid] = c;
            sf[b][tid] = beta[bl * DIM + tid] - mu * c;
        }
    }
    if (tid < 64) { slog[tid][0] = 0.f; slog[tid][1] = 0.f; slog[tid][2] = 0.f; }
    __syncthreads();

    // stage stack tiles: St[b] = bn(h_pre) + xh
    for (int i = tid; i < 1024; i += 256) {
        int r = i >> 4, c8 = (i & 15) * 8;
        int n = r0 + r;
        if (n < NNODE) {
            us8 xv = *(const us8*)(xh + (size_t)n * DIM + c8);
#pragma unroll
            for (int b = 0; b < NB; ++b) {
                const u16* src = (b == 0)
                    ? hpre0 + (size_t)n * DIM + c8
                    : ((tile == TILESN - 1) ? tailb : hpre12 + (size_t)tile * 16384)
                      + (size_t)(b - 1) * 8192 + r * DIM + c8;
                us8 hv = *(const us8*)src;
                us8 o;
#pragma unroll
                for (int j = 0; j < 8; ++j)
                    o[j] = f2h(h2f(hv[j]) * sc[b][c8 + j] + sf[b][c8 + j] + h2f(xv[j]));
                *(us8*)&St[b][r][c8] = o;
            }
        } else {
            us8 z = (us8)(u16)0;
#pragma unroll
            for (int b = 0; b < NB; ++b) *(us8*)&St[b][r][c8] = z;
        }
    }
    __syncthreads();

    const int wave = tid >> 6, lane = tid & 63, q = lane >> 4, rlo = lane & 15;
    const int col0 = wave * 32 + rlo, col1 = col0 + 16;
    const f16x8 zf = (f16x8)(f16)0.f;

    // Q GEMM: A = xh (global, L1-hot), B = wt_q
    f32x4 qa[4][2];
#pragma unroll
    for (int t = 0; t < 4; ++t) { qa[t][0] = (f32x4)0.f; qa[t][1] = (f32x4)0.f; }
#pragma unroll
    for (int kc = 0; kc < DIM; kc += 32) {
        f16x8 bv0 = *(const f16x8*)(wt_q + (size_t)(wave * 32 + rlo) * DIM + kc + q * 8);
        f16x8 bv1 = *(const f16x8*)(wt_q + (size_t)(wave * 32 + 16 + rlo) * DIM + kc + q * 8);
#pragma unroll
        for (int t = 0; t < 4; ++t) {
            int rr = r0 + 16 * t + rlo;
            f16x8 av = (rr < NNODE) ? *(const f16x8*)(xh + (size_t)rr * DIM + kc + q * 8) : zf;
            qa[t][0] = __builtin_amdgcn_mfma_f32_16x16x32_f16(av, bv0, qa[t][0], 0, 0, 0);
            qa[t][1] = __builtin_amdgcn_mfma_f32_16x16x32_f16(av, bv1, qa[t][1], 0, 0, 0);
        }
    }
    {
        const float qb0 = query_b[col0], qb1 = query_b[col1];
#pragma unroll
        for (int t = 0; t < 4; ++t)
#pragma unroll
            for (int r = 0; r < 4; ++r) { qa[t][0][r] += qb0; qa[t][1][r] += qb1; }
    }

    // K GEMMs + logits into LDS
#pragma unroll
    for (int b = 0; b < NB; ++b) {
        f32x4 ka[4][2];
#pragma unroll
        for (int t = 0; t < 4; ++t) { ka[t][0] = (f32x4)0.f; ka[t][1] = (f32x4)0.f; }
        const u16* Wk = wt_key + (size_t)b * 16384;
#pragma unroll
        for (int kc = 0; kc < DIM; kc += 32) {
            f16x8 bv0 = *(const f16x8*)(Wk + (size_t)(wave * 32 + rlo) * DIM + kc + q * 8);
            f16x8 bv1 = *(const f16x8*)(Wk + (size_t)(wave * 32 + 16 + rlo) * DIM + kc + q * 8);
#pragma unroll
            for (int t = 0; t < 4; ++t) {
                f16x8 av = *(const f16x8*)&St[b][16 * t + rlo][kc + q * 8];
                ka[t][0] = __builtin_amdgcn_mfma_f32_16x16x32_f16(av, bv0, ka[t][0], 0, 0, 0);
                ka[t][1] = __builtin_amdgcn_mfma_f32_16x16x32_f16(av, bv1, ka[t][1], 0, 0, 0);
            }
        }
        const float kb0 = key_b[b * DIM + col0], kb1 = key_b[b * DIM + col1];
#pragma unroll
        for (int t = 0; t < 4; ++t) {
#pragma unroll
            for (int r = 0; r < 4; ++r) {
                int rloc = 16 * t + q * 4 + r;
                float v = (ka[t][0][r] + kb0) * qa[t][0][r]
                        + (ka[t][1][r] + kb1) * qa[t][1][r];
                v += __shfl_xor(v, 1);
                v += __shfl_xor(v, 2);
                v += __shfl_xor(v, 4);
                v += __shfl_xor(v, 8);
                if (rlo == 0) atomicAdd(&slog[rloc][b], v);
            }
        }
    }
    __syncthreads();

    if (tid < 64) {
        float l0 = slog[tid][0], l1 = slog[tid][1], l2 = slog[tid][2];
        float mm = fmaxf(l0, fmaxf(l1, l2));
        float e0 = expf(l0 - mm), e1 = expf(l1 - mm), e2 = expf(l2 - mm);
        float inv = 1.0f / (e0 + e1 + e2);
        swt[tid][0] = e0 * inv; swt[tid][1] = e1 * inv; swt[tid][2] = e2 * inv;
    }
    __syncthreads();

    // fuse GEMM: facc = sum_b w_b * (St_b @ Wf)
    f32x4 facc[4][2];
#pragma unroll
    for (int t = 0; t < 4; ++t) { facc[t][0] = (f32x4)0.f; facc[t][1] = (f32x4)0.f; }
#pragma unroll
    for (int b = 0; b < NB; ++b) {
        f32x4 ga[4][2];
#pragma unroll
        for (int t = 0; t < 4; ++t) { ga[t][0] = (f32x4)0.f; ga[t][1] = (f32x4)0.f; }
#pragma unroll
        for (int kc = 0; kc < DIM; kc += 32) {
            f16x8 bv0 = *(const f16x8*)(wt_fuse + (size_t)(wave * 32 + rlo) * DIM + kc + q * 8);
            f16x8 bv1 = *(const f16x8*)(wt_fuse + (size_t)(wave * 32 + 16 + rlo) * DIM + kc + q * 8);
#pragma unroll
            for (int t = 0; t < 4; ++t) {
                f16x8 av = *(const f16x8*)&St[b][16 * t + rlo][kc + q * 8];
                ga[t][0] = __builtin_amdgcn_mfma_f32_16x16x32_f16(av, bv0, ga[t][0], 0, 0, 0);
                ga[t][1] = __builtin_amdgcn_mfma_f32_16x16x32_f16(av, bv1, ga[t][1], 0, 0, 0);
            }
        }
#pragma unroll
        for (int t = 0; t < 4; ++t) {
#pragma unroll
            for (int r = 0; r < 4; ++r) {
                int rloc = 16 * t + q * 4 + r;
                float wgt = swt[rloc][b];
                facc[t][0][r] += wgt * ga[t][0][r];
                facc[t][1][r] += wgt * ga[t][1][r];
            }
        }
    }
    __syncthreads();   // all St reads done before Rt overwrite

    // round fused to f16 into St[0] (Rt) for the refine GEMM
    {
        const float fb0 = fuse_b[col0], fb1 = fuse_b[col1];
#pragma unroll
        for (int t = 0; t < 4; ++t) {
#pragma unroll
            for (int r = 0; r < 4; ++r) {
                int rloc = 16 * t + q * 4 + r;
                St[0][rloc][col0] = f2h(facc[t][0][r] + fb0);
                St[0][rloc][col1] = f2h(facc[t][1][r] + fb1);
            }
        }
    }
    __syncthreads();

    // refine GEMM + ReLU -> f32 out (overwrites this tile's d_out block)
    f32x4 racc[4][2];
#pragma unroll
    for (int t = 0; t < 4; ++t) { racc[t][0] = (f32x4)0.f; racc[t][1] = (f32x4)0.f; }
#pragma unroll
    for (int kc = 0; kc < DIM; kc += 32) {
        f16x8 bv0 = *(const f16x8*)(wt_ref + (size_t)(wave * 32 + rlo) * DIM + kc + q * 8);
        f16x8 bv1 = *(const f16x8*)(wt_ref + (size_t)(wave * 32 + 16 + rlo) * DIM + kc + q * 8);
#pragma unroll
        for (int t = 0; t < 4; ++t) {
            f16x8 av = *(const f16x8*)&St[0][16 * t + rlo][kc + q * 8];
            racc[t][0] = __builtin_amdgcn_mfma_f32_16x16x32_f16(av, bv0, racc[t][0], 0, 0, 0);
            racc[t][1] = __builtin_amdgcn_mfma_f32_16x16x32_f16(av, bv1, racc[t][1], 0, 0, 0);
        }
    }
    {
        const float rb0 = refine_b[col0], rb1 = refine_b[col1];
#pragma unroll
        for (int t = 0; t < 4; ++t) {
#pragma unroll
            for (int r = 0; r < 4; ++r) {
                int row = r0 + 16 * t + q * 4 + r;
                if (row >= NNODE) continue;
                out[(size_t)row * DIM + col0] = fmaxf(racc[t][0][r] + rb0, 0.f);
                out[(size_t)row * DIM + col1] = fmaxf(racc[t][1][r] + rb1, 0.f);
            }
        }
    }
}

// ---------------- plain MFMA GEMM (fp16 weights), 64x128 tile ----------------
// flags: 1=relu, 8=A f32, 32=C f16 (else f32)

__global__ __launch_bounds__(256) void gemm_p(
    const void* __restrict__ Av, const u16* __restrict__ Wt,
    const float* __restrict__ bias, void* __restrict__ Cv, int M, int flags) {
    const u16* A16 = (const u16*)Av;
    const float* A32 = (const float*)Av;
    const float* bs = bias;
    const int r0 = blockIdx.x * 64;
    const int tid = threadIdx.x;
    const int wave = tid >> 6, lane = tid & 63, q = lane >> 4, rlo = lane & 15;
    f32x4 acc[4][2];
#pragma unroll
    for (int t = 0; t < 4; ++t) { acc[t][0] = (f32x4)0.f; acc[t][1] = (f32x4)0.f; }
    const f16x8 zf = (f16x8)(f16)0.f;
#pragma unroll
    for (int kc = 0; kc < DIM; kc += 32) {
        f16x8 av[4], bv[2];
#pragma unroll
        for (int t = 0; t < 4; ++t) {
            int row = r0 + 16 * t + rlo;
            if (row < M) {
                if (flags & 8) {
                    const float* p = A32 + (size_t)row * DIM + kc + q * 8;
                    float4 x0 = *(const float4*)p;
                    float4 x1 = *(const float4*)(p + 4);
                    f16x8 tmp;
                    tmp[0] = (f16)x0.x; tmp[1] = (f16)x0.y; tmp[2] = (f16)x0.z; tmp[3] = (f16)x0.w;
                    tmp[4] = (f16)x1.x; tmp[5] = (f16)x1.y; tmp[6] = (f16)x1.z; tmp[7] = (f16)x1.w;
                    av[t] = tmp;
                } else {
                    av[t] = *(const f16x8*)(A16 + (size_t)row * DIM + kc + q * 8);
                }
            } else {
                av[t] = zf;
            }
        }
#pragma unroll
        for (int c = 0; c < 2; ++c)
            bv[c] = *(const f16x8*)(Wt + (size_t)(wave * 32 + 16 * c + rlo) * DIM + kc + q * 8);
#pragma unroll
        for (int t = 0; t < 4; ++t) {
            acc[t][0] = __builtin_amdgcn_mfma_f32_16x16x32_f16(av[t], bv[0], acc[t][0], 0, 0, 0);
            acc[t][1] = __builtin_amdgcn_mfma_f32_16x16x32_f16(av[t], bv[1], acc[t][1], 0, 0, 0);
        }
    }

    const int col0 = wave * 32 + rlo, col1 = col0 + 16;
    const float bb0 = bs[col0], bb1 = bs[col1];
#pragma unroll
    for (int t = 0; t < 4; ++t) {
#pragma unroll
        for (int r = 0; r < 4; ++r) {
            int row = r0 + 16 * t + q * 4 + r;
            if (row >= M) continue;
            float v0 = acc[t][0][r] + bb0;
            float v1 = acc[t][1][r] + bb1;
            if (flags & 1) { v0 = fmaxf(v0, 0.f); v1 = fmaxf(v1, 0.f); }
            if (flags & 32) {
                ((u16*)Cv)[(size_t)row * DIM + col0] = f2h(v0);
                ((u16*)Cv)[(size_t)row * DIM + col1] = f2h(v1);
            } else {
                ((float*)Cv)[(size_t)row * DIM + col0] = v0;
                ((float*)Cv)[(size_t)row * DIM + col1] = v1;
            }
        }
    }
}

// ---------------- launch ----------------

extern "C" void kernel_launch(void* const* d_in, const int* in_sizes, int n_in,
                              void* d_out, int out_size, void* d_ws, size_t ws_size,
                              hipStream_t stream) {
    const int* edge_index    = (const int*)d_in[0];
    const int* edge_type     = (const int*)d_in[1];
    const float* item_feats  = (const float*)d_in[2];
    const float* user_emb    = (const float*)d_in[3];
    const float* user_proj_b = (const float*)d_in[5];
    const float* item_proj_b = (const float*)d_in[7];
    const float* sage_bl  = (const float*)d_in[9];
    const float* bn_gamma = (const float*)d_in[11];
    const float* bn_beta  = (const float*)d_in[12];
    const float* query_b  = (const float*)d_in[14];
    const float* key_b    = (const float*)d_in[16];
    const float* fuse_b   = (const float*)d_in[18];
    const float* refine_b = (const float*)d_in[20];
    const int E = in_sizes[1];

    const size_t ND = (size_t)NNODE * DIM;
    char* w = (char*)d_ws;
    u16* xh = (u16*)w;          w += ND * 2;              // initial x, fp16
    u16* stackb = (u16*)w;      w += NB * ND * 2;         // pre-BN l0 h -> activated l0
    u16* fbuf = (u16*)w;        w += ND * 2;              // h_pre layer1 slice 0
    int* cnt = (int*)w;         w += (size_t)NT3P * 4;
    int* row_start = (int*)w;   w += (size_t)NT3P * 4;
    int* cur = (int*)w;         w += (size_t)NT3P * 4;
    int* adj = (int*)w;         w += (size_t)E * 4;
    u16* wt = (u16*)w;          w += (size_t)20 * 16384 * 2;
    int* bsum = (int*)w;        w += 2048;
    float* stats6 = (float*)w;  w += 6 * 256 * 4;
    u16* tailb = (u16*)w;       w += 32768;               // last-tile h_pre slices 1,2

    const u16* wt_user = wt;
    const u16* wt_item = wt + 16384;
    const u16* wt_Wl   = wt + 2 * 16384;
    const u16* wt_Wr   = wt + 8 * 16384;

    u16* dout16 = (u16*)d_out;   // during SAGE L1: tiled h_pre slices 1,2; then final f32 out

    // ---- CSR build + weight conversion ----
    hipMemsetAsync(cnt, 0, (size_t)NT3P * 4, stream);
    hipMemsetAsync(stats6, 0, 6 * 256 * 4, stream);
    int gE = (E + 255) / 256;
    count_edges<<<gE, 256, 0, stream>>>(edge_index, edge_type, E, cnt);
    scan1<<<SCAN_BLOCKS, 256, 0, stream>>>(cnt, bsum);
    scan2<<<1, 512, 0, stream>>>(bsum, SCAN_BLOCKS);
    scan3<<<SCAN_BLOCKS, 256, 0, stream>>>(cnt, bsum, row_start, cur);
    scatter_csr<<<gE, 256, 0, stream>>>(edge_index, edge_type, E, cur, adj);

    WPtrs wp;
    wp.s[0] = (const float*)d_in[4];
    wp.s[1] = (const float*)d_in[6];
    wp.s[2] = (const float*)d_in[8];
    wp.s[3] = (const float*)d_in[10];
    wp.s[4] = (const float*)d_in[13];
    wp.s[5] = (const float*)d_in[15];
    wp.s[6] = (const float*)d_in[17];
    wp.s[7] = (const float*)d_in[19];
    wconv_all<<<1280, 256, 0, stream>>>(wp, wt);

    // ---- initial projection (f32 in, fp16 out) ----
    const int TU = (NUSER + 63) / 64, TI = (NITEM + 63) / 64;
    gemm_p<<<TU, 256, 0, stream>>>(user_emb, wt_user, user_proj_b, xh, NUSER, 8 | 32);
    gemm_p<<<TI, 256, 0, stream>>>(item_feats, wt_item, item_proj_b,
                                   xh + (size_t)NUSER * DIM, NITEM, 8 | 32);

    // ---- SAGE: layer0 -> activate in place -> layer1 ----
    Out3 out_l0, out_l1;
    for (int b = 0; b < NB; ++b) out_l0.p[b] = stackb + (size_t)b * ND;
    out_l1.p[0] = fbuf;
    out_l1.p[1] = dout16;   // tiled layout
    out_l1.p[2] = tailb;    // last tile

    sage_layer<<<NB * TILESN, 256, 0, stream>>>(xh, wt_Wl, wt_Wr, sage_bl,
                                                stats6, out_l0, 0,
                                                adj, row_start, cnt);
    bn_apply<<<NB * BNABLK, 256, 0, stream>>>(stackb, stats6, bn_gamma, bn_beta);
    sage_layer<<<NB * TILESN, 256, 0, stream>>>(stackb, wt_Wl, wt_Wr, sage_bl,
                                                stats6, out_l1, 1,
                                                adj, row_start, cnt);

    // ---- fused attention epilogue: BN+residual, logits, softmax, fuse, refine ----
    attn_fuse<<<TILESN, 256, 0, stream>>>(fbuf, dout16, tailb, stats6,
                                          bn_gamma, bn_beta, xh, wt,
                                          query_b, key_b, fuse_b, refine_b,
                                          (float*)d_out);
}